// Round 8
// baseline (284.800 us; speedup 1.0000x reference)
//
#include <hip/hip_runtime.h>

// MHA: BS=4 SEQ=2048 D_MODEL=1024 H=16 DH=64
// R8: Q/K/V projections fused into ONE dispatch (grid 8x64x3) -> 1536 blocks
// (5 resident/CU vs 2) so cross-GEMM TLP hides the 2-barrier K-step stalls.
// z=0: Q-proj (A=Qf f32, B=Wq bf16, out split-head, scaled)
// z=1: K-proj (A=Kf f32, B=Wk bf16, out split-head)
// z=2: V-proj transposed (A=Wv bf16, B=Vf f32, out (b,h,dh,s))
// attn unchanged from R7 (reg-staged dbuf + no-max softmax).
// out-proj unchanged (gemm_bt MODE2).

typedef __attribute__((ext_vector_type(8))) unsigned short us8;
typedef __attribute__((ext_vector_type(4))) unsigned short us4;
typedef __attribute__((ext_vector_type(4))) int i4;
typedef __attribute__((ext_vector_type(4))) float f4;
typedef __attribute__((ext_vector_type(4))) float f32x4;
typedef __attribute__((ext_vector_type(8))) __bf16 bf16x8;
typedef __attribute__((ext_vector_type(2))) unsigned u32x2;
typedef __attribute__((ext_vector_type(4))) unsigned u32x4;

#define DEV static __device__ __forceinline__

DEV unsigned short f2bf(float f){
  unsigned u = __builtin_bit_cast(unsigned, f);
  u = (u + 0x7fffu + ((u >> 16) & 1u)) >> 16;
  return (unsigned short)u;
}

DEV bf16x8 ld_frag(const unsigned short* p){
  return __builtin_bit_cast(bf16x8, *(const us8*)p);
}

// async global->LDS, 16B per lane. LDS dest wave-uniform base + lane*16; global src per-lane.
DEV void gll16(const unsigned short* gsrc, unsigned short* ldst){
  __builtin_amdgcn_global_load_lds(
      (const __attribute__((address_space(1))) unsigned int*)gsrc,
      (__attribute__((address_space(3))) unsigned int*)ldst, 16, 0, 0);
}

// load 8 f32, convert to 8 bf16 via packed cvt (RNE)
DEV us8 ld_cvt_f32x8(const float* p){
  f4 v0 = *(const f4*)p;
  f4 v1 = *(const f4*)(p + 4);
  unsigned d0, d1, d2, d3;
  asm("v_cvt_pk_bf16_f32 %0, %1, %2" : "=v"(d0) : "v"(v0[0]), "v"(v0[1]));
  asm("v_cvt_pk_bf16_f32 %0, %1, %2" : "=v"(d1) : "v"(v0[2]), "v"(v0[3]));
  asm("v_cvt_pk_bf16_f32 %0, %1, %2" : "=v"(d2) : "v"(v1[0]), "v"(v1[1]));
  asm("v_cvt_pk_bf16_f32 %0, %1, %2" : "=v"(d3) : "v"(v1[2]), "v"(v1[3]));
  u32x4 u = {d0, d1, d2, d3};
  return __builtin_bit_cast(us8, u);
}

// ---------------- f32 -> bf16 conversion (weights only) ----------------
__global__ void cvt_bf16(const float* __restrict__ in, unsigned short* __restrict__ out, int n8){
  int i = blockIdx.x * 256 + threadIdx.x;
  if(i >= n8) return;
  *(us8*)(out + (size_t)i * 8) = ld_cvt_f32x8(in + (size_t)i * 8);
}

// ---------------- Fused Q/K/V projection ----------------
// K=1024 fixed. 128x128 tile, 4 waves, 16x16x32 MFMA, XOR-swizzled LDS.
__global__ __launch_bounds__(256) void qkv_proj(
    const float* __restrict__ Qf, const float* __restrict__ Kf, const float* __restrict__ Vf,
    const unsigned short* __restrict__ Wqb, const unsigned short* __restrict__ Wkb,
    const unsigned short* __restrict__ Wvb,
    const float* __restrict__ bq, const float* __restrict__ bk, const float* __restrict__ bv,
    unsigned short* __restrict__ qs, unsigned short* __restrict__ ks,
    unsigned short* __restrict__ vT, float qscale)
{
  __shared__ __align__(16) unsigned short As[128 * 64];
  __shared__ __align__(16) unsigned short Bs[128 * 64];
  const int tid = threadIdx.x;
  const int z = blockIdx.z;
  const int mt = (z == 2) ? blockIdx.x : blockIdx.y;   // M-tile index
  const int nt = (z == 2) ? blockIdx.y : blockIdx.x;   // N-tile index
  const int w = tid >> 6, l = tid & 63, g = l >> 4, l15 = l & 15;
  const int wm = w >> 1, wn = w & 1;
  const int xsw = ((l & 7) ^ (l >> 3)) << 3;           // pre-swizzled src elem offset
  const int K = 1024;

  // operand roles per z (block-uniform)
  const float*          Afp = (z == 0) ? Qf : Kf;      // z<2: A f32 activation
  const unsigned short* Bbp = (z == 0) ? Wqb : Wkb;    // z<2: B bf16 weight
  // z==2: A bf16 = Wvb, B f32 = Vf

  f32x4 acc[4][4];
#pragma unroll
  for(int a = 0; a < 4; ++a)
#pragma unroll
    for(int b = 0; b < 4; ++b) acc[a][b] = (f32x4){0.f,0.f,0.f,0.f};

  for(int kt = 0; kt < 16; ++kt){
    __syncthreads();
    if(z < 2){
      // A: f32 reg-stage + cvt; B: bf16 gll16
#pragma unroll
      for(int i = 0; i < 4; ++i){
        int c = tid + i * 256, row = c >> 3, ch = c & 7;
        us8 va = ld_cvt_f32x8(Afp + (size_t)(mt * 128 + row) * K + kt * 64 + ch * 8);
        *(us8*)&As[row * 64 + ((ch * 8) ^ ((row & 7) << 3))] = va;
      }
#pragma unroll
      for(int j = 0; j < 4; ++j)
        gll16(Bbp + (size_t)(nt * 128 + (w << 5) + (j << 3) + (l >> 3)) * K + kt * 64 + xsw,
              &Bs[((w << 5) + (j << 3)) << 6]);
    } else {
      // A: bf16 gll16 (Wv); B: f32 reg-stage (Vf)
#pragma unroll
      for(int j = 0; j < 4; ++j)
        gll16(Wvb + (size_t)(mt * 128 + (w << 5) + (j << 3) + (l >> 3)) * K + kt * 64 + xsw,
              &As[((w << 5) + (j << 3)) << 6]);
#pragma unroll
      for(int i = 0; i < 4; ++i){
        int c = tid + i * 256, row = c >> 3, ch = c & 7;
        us8 vb = ld_cvt_f32x8(Vf + (size_t)(nt * 128 + row) * K + kt * 64 + ch * 8);
        *(us8*)&Bs[row * 64 + ((ch * 8) ^ ((row & 7) << 3))] = vb;
      }
    }
    asm volatile("s_waitcnt vmcnt(0)" ::: "memory");
    __syncthreads();
#pragma unroll
    for(int kk = 0; kk < 2; ++kk){
      bf16x8 af[4], bg[4];
#pragma unroll
      for(int mi = 0; mi < 4; ++mi){
        int row = wm * 64 + mi * 16 + l15;
        af[mi] = ld_frag(&As[row * 64 + ((kk * 32 + g * 8) ^ ((row & 7) << 3))]);
      }
#pragma unroll
      for(int ni = 0; ni < 4; ++ni){
        int row = wn * 64 + ni * 16 + l15;
        bg[ni] = ld_frag(&Bs[row * 64 + ((kk * 32 + g * 8) ^ ((row & 7) << 3))]);
      }
#pragma unroll
      for(int mi = 0; mi < 4; ++mi)
#pragma unroll
        for(int ni = 0; ni < 4; ++ni)
          acc[mi][ni] = __builtin_amdgcn_mfma_f32_16x16x32_bf16(af[mi], bg[ni], acc[mi][ni], 0, 0, 0);
    }
  }

  // epilogue
  if(z < 2){
    const float scale = (z == 0) ? qscale : 1.0f;
    const float* bias = (z == 0) ? bq : bk;
    unsigned short* out = (z == 0) ? qs : ks;
#pragma unroll
    for(int mi = 0; mi < 4; ++mi)
#pragma unroll
      for(int ni = 0; ni < 4; ++ni){
        int gmb = mt * 128 + wm * 64 + mi * 16 + g * 4;
        int gn  = nt * 128 + wn * 64 + ni * 16 + l15;
#pragma unroll
        for(int r = 0; r < 4; ++r){
          int gm = gmb + r;
          float v = (acc[mi][ni][r] + bias[gn]) * scale;
          int b = gm >> 11, s = gm & 2047, h = gn >> 6, dh = gn & 63;
          out[(size_t)(((b << 4) + h) * 2048 + s) * 64 + dh] = f2bf(v);
        }
      }
  } else {
#pragma unroll
    for(int mi = 0; mi < 4; ++mi)
#pragma unroll
      for(int ni = 0; ni < 4; ++ni){
        int gmb = mt * 128 + wm * 64 + mi * 16 + g * 4;   // d index
        int gn  = nt * 128 + wn * 64 + ni * 16 + l15;     // s index
#pragma unroll
        for(int r = 0; r < 4; ++r){
          int gm = gmb + r;
          float v = acc[mi][ni][r] + bv[gm];
          int h = gm >> 6, dh = gm & 63, b = gn >> 11, s = gn & 2047;
          vT[(size_t)(((b << 4) + h) * 64 + dh) * 2048 + s] = f2bf(v);
        }
      }
  }
}

// ---------------- GEMM: C = A @ B^T (+bias), out-proj only ----------------
template<int MODE, bool AF32, bool BF32>
__global__ __launch_bounds__(256) void gemm_bt(
    const void* __restrict__ Ap, const void* __restrict__ Bp,
    const float* __restrict__ bias, void* __restrict__ outp,
    int M, int N, int K, float scale)
{
  __shared__ __align__(16) unsigned short As[128 * 64];
  __shared__ __align__(16) unsigned short Bs[128 * 64];
  const int tid = threadIdx.x;
  const int gx = blockIdx.x, gy = blockIdx.y;
  const int w = tid >> 6, l = tid & 63, g = l >> 4, l15 = l & 15;
  const int wm = w >> 1, wn = w & 1;
  const int xsw = ((l & 7) ^ (l >> 3)) << 3;

  f32x4 acc[4][4];
#pragma unroll
  for(int a = 0; a < 4; ++a)
#pragma unroll
    for(int b = 0; b < 4; ++b) acc[a][b] = (f32x4){0.f,0.f,0.f,0.f};

  const int nkt = K >> 6;
  for(int kt = 0; kt < nkt; ++kt){
    __syncthreads();
    {
      const unsigned short* Ab = (const unsigned short*)Ap;
#pragma unroll
      for(int j = 0; j < 4; ++j)
        gll16(Ab + (size_t)(gy * 128 + (w << 5) + (j << 3) + (l >> 3)) * K + kt * 64 + xsw,
              &As[((w << 5) + (j << 3)) << 6]);
      const unsigned short* Bb = (const unsigned short*)Bp;
#pragma unroll
      for(int j = 0; j < 4; ++j)
        gll16(Bb + (size_t)(gx * 128 + (w << 5) + (j << 3) + (l >> 3)) * K + kt * 64 + xsw,
              &Bs[((w << 5) + (j << 3)) << 6]);
    }
    asm volatile("s_waitcnt vmcnt(0)" ::: "memory");
    __syncthreads();
#pragma unroll
    for(int kk = 0; kk < 2; ++kk){
      bf16x8 af[4], bg[4];
#pragma unroll
      for(int mi = 0; mi < 4; ++mi){
        int row = wm * 64 + mi * 16 + l15;
        af[mi] = ld_frag(&As[row * 64 + ((kk * 32 + g * 8) ^ ((row & 7) << 3))]);
      }
#pragma unroll
      for(int ni = 0; ni < 4; ++ni){
        int row = wn * 64 + ni * 16 + l15;
        bg[ni] = ld_frag(&Bs[row * 64 + ((kk * 32 + g * 8) ^ ((row & 7) << 3))]);
      }
#pragma unroll
      for(int mi = 0; mi < 4; ++mi)
#pragma unroll
        for(int ni = 0; ni < 4; ++ni)
          acc[mi][ni] = __builtin_amdgcn_mfma_f32_16x16x32_bf16(af[mi], bg[ni], acc[mi][ni], 0, 0, 0);
    }
  }

#pragma unroll
  for(int mi = 0; mi < 4; ++mi)
#pragma unroll
    for(int ni = 0; ni < 4; ++ni){
      int gmb = gy * 128 + wm * 64 + mi * 16 + g * 4;
      int gn  = gx * 128 + wn * 64 + ni * 16 + l15;
#pragma unroll
      for(int r = 0; r < 4; ++r){
        int gm = gmb + r;
        float v = acc[mi][ni][r] + bias[gn];
        ((float*)outp)[(size_t)gm * N + gn] = v;
      }
    }
}

// ---------------- Flash attention (unchanged from R7) ----------------
__global__ __launch_bounds__(256) void attn_kernel(
    const unsigned short* __restrict__ q, const unsigned short* __restrict__ k,
    const unsigned short* __restrict__ vT, const int* __restrict__ mask,
    unsigned short* __restrict__ ctx)
{
  __shared__ __align__(16) unsigned short KsB[2][64 * 64];
  __shared__ __align__(16) unsigned short VtB[2][64 * 64];
  __shared__ __align__(16) unsigned short Ps[4][16 * 64];
  __shared__ __align__(16) float smaskf[2048];

  const int qt = blockIdx.x;
  const int bh = blockIdx.y;
  const int b  = bh >> 4, h = bh & 15;
  const int tid = threadIdx.x;
  const int w = tid >> 6, l = tid & 63, g = l >> 4, l15 = l & 15;
  const int rl = l >> 3, c8 = l & 7;

  const unsigned short* qbase = q + ((size_t)(bh * 2048 + qt * 64 + w * 16 + l15)) * 64;
  bf16x8 bq[2];
  bq[0] = ld_frag(qbase + g * 8);
  bq[1] = ld_frag(qbase + 32 + g * 8);

  const unsigned short* kbase = k  + (size_t)bh * 2048 * 64;
  const unsigned short* vbase = vT + (size_t)bh * 64 * 2048;

  const unsigned short* kg0 = kbase + (size_t)(w * 16 + rl) * 64 + c8 * 8;
  const unsigned short* vg0 = vbase + (size_t)(w * 16 + rl) * 2048 + c8 * 8;
  const int lo0 = (w * 16 + rl) * 64 + ((c8 ^ rl) << 3);
  const int lo1 = lo0 + 8 * 64;

  us8 kr0, kr1, vr0, vr1;
#define LOAD_T(kt_) do{                                        \
    kr0 = *(const us8*)(kg0 + (size_t)(kt_) * 4096);           \
    kr1 = *(const us8*)(kg0 + (size_t)(kt_) * 4096 + 512);     \
    vr0 = *(const us8*)(vg0 + (size_t)(kt_) * 64);             \
    vr1 = *(const us8*)(vg0 + (size_t)(kt_) * 64 + 8 * 2048);  \
  }while(0)
#define WRITE_T(bb_) do{                                       \
    *(us8*)&KsB[bb_][lo0] = kr0;                               \
    *(us8*)&KsB[bb_][lo1] = kr1;                               \
    *(us8*)&VtB[bb_][lo0] = vr0;                               \
    *(us8*)&VtB[bb_][lo1] = vr1;                               \
  }while(0)

  {
    int i0 = tid * 8;
    i4 m0 = *(const i4*)&mask[b * 2048 + i0];
    i4 m1 = *(const i4*)&mask[b * 2048 + i0 + 4];
    f4 f0, f1;
#pragma unroll
    for(int r = 0; r < 4; ++r){
      f0[r] = m0[r] ? 0.f : -1.44269502e9f;
      f1[r] = m1[r] ? 0.f : -1.44269502e9f;
    }
    *(f4*)&smaskf[i0] = f0;
    *(f4*)&smaskf[i0 + 4] = f1;
  }

  f32x4 acc[4];
#pragma unroll
  for(int mi = 0; mi < 4; ++mi) acc[mi] = (f32x4){0.f,0.f,0.f,0.f};
  float ll = 0.f;

  LOAD_T(0);
  WRITE_T(0);
  __syncthreads();

  for(int kt = 0; kt < 32; ++kt){
    const int bb = kt & 1;
    if(kt < 31) LOAD_T(kt + 1);

    f32x4 sa[4];
#pragma unroll
    for(int mi = 0; mi < 4; ++mi) sa[mi] = (f32x4){0.f,0.f,0.f,0.f};
#pragma unroll
    for(int kk = 0; kk < 2; ++kk){
#pragma unroll
      for(int mi = 0; mi < 4; ++mi){
        int row = mi * 16 + l15;
        bf16x8 af = ld_frag(&KsB[bb][row * 64 + ((kk * 32 + g * 8) ^ ((row & 7) << 3))]);
        sa[mi] = __builtin_amdgcn_mfma_f32_16x16x32_bf16(af, bq[kk], sa[mi], 0, 0, 0);
      }
    }

    float p[4][4];
#pragma unroll
    for(int mi = 0; mi < 4; ++mi){
      f4 mf = *(const f4*)&smaskf[kt * 64 + mi * 16 + g * 4];
#pragma unroll
      for(int r = 0; r < 4; ++r){
        p[mi][r] = __builtin_amdgcn_exp2f(sa[mi][r] + mf[r]);
        ll += p[mi][r];
      }
    }

#pragma unroll
    for(int mi = 0; mi < 4; ++mi){
      unsigned d0, d1;
      asm("v_cvt_pk_bf16_f32 %0, %1, %2" : "=v"(d0) : "v"(p[mi][0]), "v"(p[mi][1]));
      asm("v_cvt_pk_bf16_f32 %0, %1, %2" : "=v"(d1) : "v"(p[mi][2]), "v"(p[mi][3]));
      u32x2 dd = {d0, d1};
      *(u32x2*)&Ps[w][l15 * 64 + ((mi * 16 + g * 4) ^ ((l15 & 7) << 3))] = dd;
    }

#pragma unroll
    for(int kk = 0; kk < 2; ++kk){
      bf16x8 pb = ld_frag(&Ps[w][l15 * 64 + ((kk * 32 + g * 8) ^ ((l15 & 7) << 3))]);
#pragma unroll
      for(int mi = 0; mi < 4; ++mi){
        int row = mi * 16 + l15;
        bf16x8 av = ld_frag(&VtB[bb][row * 64 + ((kk * 32 + g * 8) ^ ((row & 7) << 3))]);
        acc[mi] = __builtin_amdgcn_mfma_f32_16x16x32_bf16(av, pb, acc[mi], 0, 0, 0);
      }
    }

    if(kt < 31) WRITE_T(bb ^ 1);
    __syncthreads();
  }

  ll += __shfl_xor(ll, 16);
  ll += __shfl_xor(ll, 32);
  float inv = 1.0f / ll;

  {
    int qrow = w * 16 + l15;
#pragma unroll
    for(int mi = 0; mi < 4; ++mi){
      us4 o;
#pragma unroll
      for(int r = 0; r < 4; ++r) o[r] = f2bf(acc[mi][r] * inv);
      *(us4*)&KsB[0][qrow * 64 + ((mi * 16 + g * 4) ^ ((qrow & 7) << 3))] = o;
    }
  }
  __syncthreads();
  {
    int qrow = tid >> 2, part = tid & 3;
    us8 v0 = *(const us8*)&KsB[0][qrow * 64 + ((part * 16)     ^ ((qrow & 7) << 3))];
    us8 v1 = *(const us8*)&KsB[0][qrow * 64 + ((part * 16 + 8) ^ ((qrow & 7) << 3))];
    size_t orow = ((size_t)b * 2048 + qt * 64 + qrow) * 1024 + h * 64 + part * 16;
    *(us8*)&ctx[orow] = v0;
    *(us8*)&ctx[orow + 8] = v1;
  }
#undef LOAD_T
#undef WRITE_T
}

// ---------------- launch ----------------
extern "C" void kernel_launch(void* const* d_in, const int* in_sizes, int n_in,
                              void* d_out, int out_size, void* d_ws, size_t ws_size,
                              hipStream_t stream) {
  const float* Qf = (const float*)d_in[0];
  const float* Kf = (const float*)d_in[1];
  const float* Vf = (const float*)d_in[2];
  const int*   Mk = (const int*)d_in[3];
  const float* Wq = (const float*)d_in[4];
  const float* bq = (const float*)d_in[5];
  const float* Wk = (const float*)d_in[6];
  const float* bk = (const float*)d_in[7];
  const float* Wv = (const float*)d_in[8];
  const float* bv = (const float*)d_in[9];
  const float* Wo = (const float*)d_in[10];
  const float* bo = (const float*)d_in[11];

  const size_t MB = 1u << 20;
  char* ws = (char*)d_ws;
  unsigned short* Wqb = (unsigned short*)(ws + 0 * MB);
  unsigned short* Wkb = (unsigned short*)(ws + 2 * MB);
  unsigned short* Wvb = (unsigned short*)(ws + 4 * MB);
  unsigned short* Wob = (unsigned short*)(ws + 6 * MB);
  unsigned short* qs  = (unsigned short*)(ws + 8 * MB);
  unsigned short* ks  = (unsigned short*)(ws + 24 * MB);
  unsigned short* vT  = (unsigned short*)(ws + 40 * MB);
  unsigned short* ctx = (unsigned short*)(ws + 56 * MB);

  const int NW = 1024 * 1024;

  auto cvt = [&](const float* src, unsigned short* dst, int n){
    int n8 = n / 8;
    cvt_bf16<<<(n8 + 255) / 256, 256, 0, stream>>>(src, dst, n8);
  };
  cvt(Wq, Wqb, NW);
  cvt(Wk, Wkb, NW);
  cvt(Wv, Wvb, NW);
  cvt(Wo, Wob, NW);

  const float QSCALE = 0.125f * 1.4426950408889634f;  // 1/sqrt(d_head) * log2(e)
  dim3 blk(256);
  // fused Q/K/V projections: 1536 blocks
  qkv_proj<<<dim3(8, 64, 3), blk, 0, stream>>>(Qf, Kf, Vf, Wqb, Wkb, Wvb,
                                               bq, bk, bv, qs, ks, vT, QSCALE);
  // attention
  attn_kernel<<<dim3(32, 64), blk, 0, stream>>>(qs, ks, vT, Mk, ctx);
  // output projection -> f32
  gemm_bt<2, false, false><<<dim3(8, 64), blk, 0, stream>>>(ctx, Wob, bo, d_out, 8192, 1024, 1024, 1.0f);
}

// Round 9
// 207.281 us; speedup vs baseline: 1.3740x; 1.3740x over previous
//
#include <hip/hip_runtime.h>

// MHA: BS=4 SEQ=2048 D_MODEL=1024 H=16 DH=64
// R9 = R7 (fusion reverted) + MASK COMPACTION:
//   mask_scan: per-batch list of unmasked key indices + count nk[b] (~50%).
//   K-proj / V-proj gather activation rows via idx -> compacted ksc/vTc
//   (those GEMMs ~halve: blocks past the compacted range exit).
//   attn iterates ceil(nk/64) tiles (~17 vs 32), tail tile uses compare-select.
// Exact: masked keys have P == 0 (exp2(-1e9) == 0) in numerator & denominator.

typedef __attribute__((ext_vector_type(8))) unsigned short us8;
typedef __attribute__((ext_vector_type(4))) unsigned short us4;
typedef __attribute__((ext_vector_type(4))) int i4;
typedef __attribute__((ext_vector_type(4))) float f4;
typedef __attribute__((ext_vector_type(4))) float f32x4;
typedef __attribute__((ext_vector_type(8))) __bf16 bf16x8;
typedef __attribute__((ext_vector_type(2))) unsigned u32x2;
typedef __attribute__((ext_vector_type(4))) unsigned u32x4;

#define DEV static __device__ __forceinline__

DEV unsigned short f2bf(float f){
  unsigned u = __builtin_bit_cast(unsigned, f);
  u = (u + 0x7fffu + ((u >> 16) & 1u)) >> 16;
  return (unsigned short)u;
}

DEV bf16x8 ld_frag(const unsigned short* p){
  return __builtin_bit_cast(bf16x8, *(const us8*)p);
}

// async global->LDS, 16B per lane. LDS dest wave-uniform base + lane*16; global src per-lane.
DEV void gll16(const unsigned short* gsrc, unsigned short* ldst){
  __builtin_amdgcn_global_load_lds(
      (const __attribute__((address_space(1))) unsigned int*)gsrc,
      (__attribute__((address_space(3))) unsigned int*)ldst, 16, 0, 0);
}

// load 8 f32, convert to 8 bf16 via packed cvt (RNE)
DEV us8 ld_cvt_f32x8(const float* p){
  f4 v0 = *(const f4*)p;
  f4 v1 = *(const f4*)(p + 4);
  unsigned d0, d1, d2, d3;
  asm("v_cvt_pk_bf16_f32 %0, %1, %2" : "=v"(d0) : "v"(v0[0]), "v"(v0[1]));
  asm("v_cvt_pk_bf16_f32 %0, %1, %2" : "=v"(d1) : "v"(v0[2]), "v"(v0[3]));
  asm("v_cvt_pk_bf16_f32 %0, %1, %2" : "=v"(d2) : "v"(v1[0]), "v"(v1[1]));
  asm("v_cvt_pk_bf16_f32 %0, %1, %2" : "=v"(d3) : "v"(v1[2]), "v"(v1[3]));
  u32x4 u = {d0, d1, d2, d3};
  return __builtin_bit_cast(us8, u);
}

// ---------------- f32 -> bf16 conversion (weights only) ----------------
__global__ void cvt_bf16(const float* __restrict__ in, unsigned short* __restrict__ out, int n8){
  int i = blockIdx.x * 256 + threadIdx.x;
  if(i >= n8) return;
  *(us8*)(out + (size_t)i * 8) = ld_cvt_f32x8(in + (size_t)i * 8);
}

// ---------------- mask scan: compacted unmasked-key index list ----------------
// one block per batch. idx[b][0..nk) = key positions with mask!=0; pad to 128.
__global__ __launch_bounds__(256) void mask_scan(
    const int* __restrict__ mask, int* __restrict__ idx, int* __restrict__ nk)
{
  const int b = blockIdx.x, t = threadIdx.x;
  __shared__ int sc[256];
  int m[8]; int c = 0;
#pragma unroll
  for(int r = 0; r < 8; ++r){ m[r] = mask[b * 2048 + t * 8 + r]; c += (m[r] != 0); }
  sc[t] = c;
  __syncthreads();
  for(int s = 1; s < 256; s <<= 1){
    int v = (t >= s) ? sc[t - s] : 0;
    __syncthreads();
    sc[t] += v;
    __syncthreads();
  }
  int pos = sc[t] - c;            // exclusive prefix
  int total = sc[255];
#pragma unroll
  for(int r = 0; r < 8; ++r) if(m[r]) idx[b * 2048 + pos++] = t * 8 + r;
  // pad to 128 boundary with a valid row (0) so gathering proj blocks never OOB
  int pend = (total + 127) & ~127;
  for(int p = total + t; p < pend; p += 256) idx[b * 2048 + p] = 0;
  if(t == 0) nk[b] = total;
}

// ---------------- GEMM: C = A @ B^T (+bias), A[M][K], B[N][K] ----------------
// GATHER: 0 none, 1 = A f32 rows gathered via idx (K-proj), 2 = B f32 rows
// gathered (V-proj). Gathered dims are per-batch compacted; blocks fully past
// roundup128(nk[b]) exit.
template<int MODE, bool AF32, bool BF32, int GATHER>
__global__ __launch_bounds__(256) void gemm_bt(
    const void* __restrict__ Ap, const void* __restrict__ Bp,
    const float* __restrict__ bias, void* __restrict__ outp,
    int M, int N, int K, float scale,
    const int* __restrict__ gidx, const int* __restrict__ nkarr)
{
  __shared__ __align__(16) unsigned short As[128 * 64];
  __shared__ __align__(16) unsigned short Bs[128 * 64];
  const int tid = threadIdx.x;
  const int gx = blockIdx.x, gy = blockIdx.y;      // gx: N-tile, gy: M-tile
  const int w = tid >> 6, l = tid & 63, g = l >> 4, l15 = l & 15;
  const int wm = w >> 1, wn = w & 1;
  const int xsw = ((l & 7) ^ (l >> 3)) << 3;

  int ia[4];                                        // gathered row indices
  int gb = 0;
  if constexpr(GATHER != 0){
    const int tilerow = (GATHER == 1) ? gy : gx;
    gb = (tilerow * 128) >> 11;
    const int j0 = (tilerow * 128) & 2047;
    const int total = nkarr[gb];
    if(j0 >= ((total + 127) & ~127)) return;        // uniform exit, pre-barrier
#pragma unroll
    for(int i = 0; i < 4; ++i)
      ia[i] = gidx[gb * 2048 + j0 + (tid >> 3) + i * 32];
  }

  f32x4 acc[4][4];
#pragma unroll
  for(int a = 0; a < 4; ++a)
#pragma unroll
    for(int b = 0; b < 4; ++b) acc[a][b] = (f32x4){0.f,0.f,0.f,0.f};

  const int ch = tid & 7;
  const int nkt = K >> 6;
  for(int kt = 0; kt < nkt; ++kt){
    __syncthreads();
    if constexpr(AF32){
#pragma unroll
      for(int i = 0; i < 4; ++i){
        int row = (tid >> 3) + i * 32;
        const float* src;
        if constexpr(GATHER == 1)
          src = (const float*)Ap + ((size_t)gb * 2048 + ia[i]) * K + kt * 64 + ch * 8;
        else
          src = (const float*)Ap + (size_t)(gy * 128 + row) * K + kt * 64 + ch * 8;
        us8 va = ld_cvt_f32x8(src);
        *(us8*)&As[row * 64 + ((ch * 8) ^ ((row & 7) << 3))] = va;
      }
    } else {
      const unsigned short* Ab = (const unsigned short*)Ap;
#pragma unroll
      for(int j = 0; j < 4; ++j)
        gll16(Ab + (size_t)(gy * 128 + (w << 5) + (j << 3) + (l >> 3)) * K + kt * 64 + xsw,
              &As[((w << 5) + (j << 3)) << 6]);
    }
    if constexpr(BF32){
#pragma unroll
      for(int i = 0; i < 4; ++i){
        int row = (tid >> 3) + i * 32;
        const float* src;
        if constexpr(GATHER == 2)
          src = (const float*)Bp + ((size_t)gb * 2048 + ia[i]) * K + kt * 64 + ch * 8;
        else
          src = (const float*)Bp + (size_t)(gx * 128 + row) * K + kt * 64 + ch * 8;
        us8 vb = ld_cvt_f32x8(src);
        *(us8*)&Bs[row * 64 + ((ch * 8) ^ ((row & 7) << 3))] = vb;
      }
    } else {
      const unsigned short* Bb = (const unsigned short*)Bp;
#pragma unroll
      for(int j = 0; j < 4; ++j)
        gll16(Bb + (size_t)(gx * 128 + (w << 5) + (j << 3) + (l >> 3)) * K + kt * 64 + xsw,
              &Bs[((w << 5) + (j << 3)) << 6]);
    }
    if constexpr(!(AF32 && BF32))
      asm volatile("s_waitcnt vmcnt(0)" ::: "memory");
    __syncthreads();
#pragma unroll
    for(int kk = 0; kk < 2; ++kk){
      bf16x8 af[4], bg[4];
#pragma unroll
      for(int mi = 0; mi < 4; ++mi){
        int row = wm * 64 + mi * 16 + l15;
        af[mi] = ld_frag(&As[row * 64 + ((kk * 32 + g * 8) ^ ((row & 7) << 3))]);
      }
#pragma unroll
      for(int ni = 0; ni < 4; ++ni){
        int row = wn * 64 + ni * 16 + l15;
        bg[ni] = ld_frag(&Bs[row * 64 + ((kk * 32 + g * 8) ^ ((row & 7) << 3))]);
      }
#pragma unroll
      for(int mi = 0; mi < 4; ++mi)
#pragma unroll
        for(int ni = 0; ni < 4; ++ni)
          acc[mi][ni] = __builtin_amdgcn_mfma_f32_16x16x32_bf16(af[mi], bg[ni], acc[mi][ni], 0, 0, 0);
    }
  }

  // epilogue
#pragma unroll
  for(int mi = 0; mi < 4; ++mi)
#pragma unroll
    for(int ni = 0; ni < 4; ++ni){
      int gmb = gy * 128 + wm * 64 + mi * 16 + g * 4;
      int gn  = gx * 128 + wn * 64 + ni * 16 + l15;
#pragma unroll
      for(int r = 0; r < 4; ++r){
        int gm = gmb + r;
        float v = acc[mi][ni][r];
        if(MODE == 0){
          v = (v + bias[gn]) * scale;
          int b = gm >> 11, s = gm & 2047, h = gn >> 6, dh = gn & 63;
          ((unsigned short*)outp)[(size_t)(((b << 4) + h) * 2048 + s) * 64 + dh] = f2bf(v);
        } else if(MODE == 1){
          v = v + bias[gm];
          int h = gm >> 6, dh = gm & 63, b = gn >> 11, s = gn & 2047;
          ((unsigned short*)outp)[(size_t)(((b << 4) + h) * 64 + dh) * 2048 + s] = f2bf(v);
        } else {
          v = v + bias[gn];
          ((float*)outp)[(size_t)gm * N + gn] = v;
        }
      }
    }
}

// ---------------- Flash attention over compacted keys ----------------
// q: (b,h,s,dh) pre-scaled by (1/8)*log2(e). ksc: (b,h,j,dh). vTc: (b,h,dh,j).
// nk[b] = valid key count. Loop ceil(nk/64) tiles; tail tile zero-selects.
__global__ __launch_bounds__(256) void attn_kernel(
    const unsigned short* __restrict__ q, const unsigned short* __restrict__ ksc,
    const unsigned short* __restrict__ vTc, const int* __restrict__ nk,
    unsigned short* __restrict__ ctx)
{
  __shared__ __align__(16) unsigned short KsB[2][64 * 64];
  __shared__ __align__(16) unsigned short VtB[2][64 * 64];
  __shared__ __align__(16) unsigned short Ps[4][16 * 64];

  const int qt = blockIdx.x;
  const int bh = blockIdx.y;
  const int b  = bh >> 4, h = bh & 15;
  const int tid = threadIdx.x;
  const int w = tid >> 6, l = tid & 63, g = l >> 4, l15 = l & 15;
  const int rl = l >> 3, c8 = l & 7;

  const int nkb = nk[b];
  const int nt = (nkb + 63) >> 6;

  const unsigned short* qbase = q + ((size_t)(bh * 2048 + qt * 64 + w * 16 + l15)) * 64;
  bf16x8 bq[2];
  bq[0] = ld_frag(qbase + g * 8);
  bq[1] = ld_frag(qbase + 32 + g * 8);

  const unsigned short* kbase = ksc + (size_t)bh * 2048 * 64;
  const unsigned short* vbase = vTc + (size_t)bh * 64 * 2048;

  const unsigned short* kg0 = kbase + (size_t)(w * 16 + rl) * 64 + c8 * 8;
  const unsigned short* vg0 = vbase + (size_t)(w * 16 + rl) * 2048 + c8 * 8;
  const int lo0 = (w * 16 + rl) * 64 + ((c8 ^ rl) << 3);
  const int lo1 = lo0 + 8 * 64;

  us8 kr0, kr1, vr0, vr1;
#define LOAD_T(kt_) do{                                        \
    kr0 = *(const us8*)(kg0 + (size_t)(kt_) * 4096);           \
    kr1 = *(const us8*)(kg0 + (size_t)(kt_) * 4096 + 512);     \
    vr0 = *(const us8*)(vg0 + (size_t)(kt_) * 64);             \
    vr1 = *(const us8*)(vg0 + (size_t)(kt_) * 64 + 8 * 2048);  \
  }while(0)
#define WRITE_T(bb_) do{                                       \
    *(us8*)&KsB[bb_][lo0] = kr0;                               \
    *(us8*)&KsB[bb_][lo1] = kr1;                               \
    *(us8*)&VtB[bb_][lo0] = vr0;                               \
    *(us8*)&VtB[bb_][lo1] = vr1;                               \
  }while(0)

  f32x4 acc[4];
#pragma unroll
  for(int mi = 0; mi < 4; ++mi) acc[mi] = (f32x4){0.f,0.f,0.f,0.f};
  float ll = 0.f;

  LOAD_T(0);
  WRITE_T(0);
  __syncthreads();

  for(int kt = 0; kt < nt; ++kt){
    const int bb = kt & 1;
    if(kt + 1 < nt) LOAD_T(kt + 1);

    f32x4 sa[4];
#pragma unroll
    for(int mi = 0; mi < 4; ++mi) sa[mi] = (f32x4){0.f,0.f,0.f,0.f};
#pragma unroll
    for(int kk = 0; kk < 2; ++kk){
#pragma unroll
      for(int mi = 0; mi < 4; ++mi){
        int row = mi * 16 + l15;
        bf16x8 af = ld_frag(&KsB[bb][row * 64 + ((kk * 32 + g * 8) ^ ((row & 7) << 3))]);
        sa[mi] = __builtin_amdgcn_mfma_f32_16x16x32_bf16(af, bq[kk], sa[mi], 0, 0, 0);
      }
    }

    float p[4][4];
    if((kt + 1) * 64 <= nkb){
      // full tile: all keys valid, no mask at all
#pragma unroll
      for(int mi = 0; mi < 4; ++mi)
#pragma unroll
        for(int r = 0; r < 4; ++r){
          p[mi][r] = __builtin_amdgcn_exp2f(sa[mi][r]);
          ll += p[mi][r];
        }
    } else {
      // tail tile: zero-select keys beyond nkb
      int kb0 = kt * 64 + g * 4;
#pragma unroll
      for(int mi = 0; mi < 4; ++mi)
#pragma unroll
        for(int r = 0; r < 4; ++r){
          float e = __builtin_amdgcn_exp2f(sa[mi][r]);
          p[mi][r] = (kb0 + mi * 16 + r < nkb) ? e : 0.f;
          ll += p[mi][r];
        }
    }

#pragma unroll
    for(int mi = 0; mi < 4; ++mi){
      unsigned d0, d1;
      asm("v_cvt_pk_bf16_f32 %0, %1, %2" : "=v"(d0) : "v"(p[mi][0]), "v"(p[mi][1]));
      asm("v_cvt_pk_bf16_f32 %0, %1, %2" : "=v"(d1) : "v"(p[mi][2]), "v"(p[mi][3]));
      u32x2 dd = {d0, d1};
      *(u32x2*)&Ps[w][l15 * 64 + ((mi * 16 + g * 4) ^ ((l15 & 7) << 3))] = dd;
    }

#pragma unroll
    for(int kk = 0; kk < 2; ++kk){
      bf16x8 pb = ld_frag(&Ps[w][l15 * 64 + ((kk * 32 + g * 8) ^ ((l15 & 7) << 3))]);
#pragma unroll
      for(int mi = 0; mi < 4; ++mi){
        int row = mi * 16 + l15;
        bf16x8 av = ld_frag(&VtB[bb][row * 64 + ((kk * 32 + g * 8) ^ ((row & 7) << 3))]);
        acc[mi] = __builtin_amdgcn_mfma_f32_16x16x32_bf16(av, pb, acc[mi], 0, 0, 0);
      }
    }

    if(kt + 1 < nt) WRITE_T(bb ^ 1);
    __syncthreads();
  }

  ll += __shfl_xor(ll, 16);
  ll += __shfl_xor(ll, 32);
  float inv = 1.0f / ll;

  {
    int qrow = w * 16 + l15;
#pragma unroll
    for(int mi = 0; mi < 4; ++mi){
      us4 o;
#pragma unroll
      for(int r = 0; r < 4; ++r) o[r] = f2bf(acc[mi][r] * inv);
      *(us4*)&KsB[0][qrow * 64 + ((mi * 16 + g * 4) ^ ((qrow & 7) << 3))] = o;
    }
  }
  __syncthreads();
  {
    int qrow = tid >> 2, part = tid & 3;
    us8 v0 = *(const us8*)&KsB[0][qrow * 64 + ((part * 16)     ^ ((qrow & 7) << 3))];
    us8 v1 = *(const us8*)&KsB[0][qrow * 64 + ((part * 16 + 8) ^ ((qrow & 7) << 3))];
    size_t orow = ((size_t)b * 2048 + qt * 64 + qrow) * 1024 + h * 64 + part * 16;
    *(us8*)&ctx[orow] = v0;
    *(us8*)&ctx[orow + 8] = v1;
  }
#undef LOAD_T
#undef WRITE_T
}

// ---------------- launch ----------------
extern "C" void kernel_launch(void* const* d_in, const int* in_sizes, int n_in,
                              void* d_out, int out_size, void* d_ws, size_t ws_size,
                              hipStream_t stream) {
  const float* Qf = (const float*)d_in[0];
  const float* Kf = (const float*)d_in[1];
  const float* Vf = (const float*)d_in[2];
  const int*   Mk = (const int*)d_in[3];
  const float* Wq = (const float*)d_in[4];
  const float* bq = (const float*)d_in[5];
  const float* Wk = (const float*)d_in[6];
  const float* bk = (const float*)d_in[7];
  const float* Wv = (const float*)d_in[8];
  const float* bv = (const float*)d_in[9];
  const float* Wo = (const float*)d_in[10];
  const float* bo = (const float*)d_in[11];

  const size_t MB = 1u << 20;
  char* ws = (char*)d_ws;
  unsigned short* Wqb = (unsigned short*)(ws + 0 * MB);
  unsigned short* Wkb = (unsigned short*)(ws + 2 * MB);
  unsigned short* Wvb = (unsigned short*)(ws + 4 * MB);
  unsigned short* Wob = (unsigned short*)(ws + 6 * MB);
  unsigned short* qs  = (unsigned short*)(ws + 8 * MB);
  unsigned short* ksc = (unsigned short*)(ws + 24 * MB);
  unsigned short* vTc = (unsigned short*)(ws + 40 * MB);
  unsigned short* ctx = (unsigned short*)(ws + 56 * MB);
  int* idx = (int*)(ws + 72 * MB);
  int* nk  = (int*)(ws + 73 * MB);

  const int NW = 1024 * 1024;

  auto cvt = [&](const float* src, unsigned short* dst, int n){
    int n8 = n / 8;
    cvt_bf16<<<(n8 + 255) / 256, 256, 0, stream>>>(src, dst, n8);
  };
  cvt(Wq, Wqb, NW);
  cvt(Wk, Wkb, NW);
  cvt(Wv, Wvb, NW);
  cvt(Wo, Wob, NW);

  mask_scan<<<4, 256, 0, stream>>>(Mk, idx, nk);

  const float QSCALE = 0.125f * 1.4426950408889634f;  // 1/sqrt(d_head) * log2(e)
  dim3 blk(256);
  // Q-proj (full)
  gemm_bt<0, true, false, 0><<<dim3(8, 64), blk, 0, stream>>>(
      Qf, Wqb, bq, qs, 8192, 1024, 1024, QSCALE, nullptr, nullptr);
  // K-proj over compacted keys (A rows gathered)
  gemm_bt<0, true, false, 1><<<dim3(8, 64), blk, 0, stream>>>(
      Kf, Wkb, bk, ksc, 8192, 1024, 1024, 1.0f, idx, nk);
  // V-proj transposed over compacted keys (B rows gathered)
  gemm_bt<1, false, true, 2><<<dim3(64, 8), blk, 0, stream>>>(
      Wvb, Vf, bv, vTc, 1024, 8192, 1024, 1.0f, idx, nk);
  // attention over compacted keys
  attn_kernel<<<dim3(32, 64), blk, 0, stream>>>(qs, ksc, vTc, nk, ctx);
  // output projection -> f32
  gemm_bt<2, false, false, 0><<<dim3(8, 64), blk, 0, stream>>>(
      ctx, Wob, bo, d_out, 8192, 1024, 1024, 1.0f, nullptr, nullptr);
}